// Round 2
// baseline (430.490 us; speedup 1.0000x reference)
//
#include <hip/hip_runtime.h>
#include <math.h>

#define T_LEN   1024
#define D_DIM   512
#define B_DIM   16
#define OUT_T   1280
#define K_SEL   16
#define NSER    (B_DIM * D_DIM)   /* 8192 series */

// d_ws layout:
//   [0, 16384)            double2 twd[1024]   W^m = e^{-2pi i m/1024} (cos, -sin)  fp64
//   [16384, 24576)        float2  twf[1024]   V^m = e^{+2pi i m/1024} (cos, +sin)  fp32
//   [24576, 24576+2MiB)   float4  sel[8192][16]  (k, re*2/N, im*2/N, 0)
//
// d_out doubles as scratch for xT (16,512,1024) fp32 = 32 MB; fully
// overwritten by k_recon at the end.

// ---------------- kernel 0: twiddle tables ----------------
__global__ void k_tables(double2* __restrict__ twd, float2* __restrict__ twf) {
    int m = blockIdx.x * blockDim.x + threadIdx.x;
    if (m >= T_LEN) return;
    const double w0 = 6.283185307179586476925286766559e0 / (double)T_LEN;
    double s, c;
    sincos(w0 * (double)m, &s, &c);
    twd[m] = make_double2(c, -s);              // e^{-i theta}
    twf[m] = make_float2((float)c, (float)s);  // e^{+i theta}
}

// ---------------- kernel T: transpose x(b,t,d) -> xT(b,d,t) ----------------
__global__ __launch_bounds__(256) void k_transpose(const float* __restrict__ x,
                                                   float* __restrict__ xT) {
    __shared__ float tile[32][33];
    int blk = blockIdx.x;            // b(16) * ttile(32) * dtile(16) = 8192
    int b  = blk >> 9;
    int tt = (blk >> 4) & 31;
    int dt = blk & 15;
    int t0 = tt * 32, d0 = dt * 32;
    int lr = threadIdx.x >> 5;       // 0..7
    int lc = threadIdx.x & 31;       // 0..31
    const float* xb = x + (size_t)b * T_LEN * D_DIM;
#pragma unroll
    for (int i = 0; i < 4; i++) {
        int row = lr + i * 8;
        tile[row][lc] = xb[(size_t)(t0 + row) * D_DIM + (d0 + lc)];
    }
    __syncthreads();
    float* xTb = xT + (size_t)b * D_DIM * T_LEN;
#pragma unroll
    for (int i = 0; i < 4; i++) {
        int row = lr + i * 8;        // d-row within tile
        xTb[(size_t)(d0 + row) * T_LEN + (t0 + lc)] = tile[lc][row];
    }
}

// ---------------- kernel 1: fp64 DFT (32x32 CT) + top-16 ----------------
__global__ __launch_bounds__(256) void k_dft_topk(const float* __restrict__ xT,
                                                  const double2* __restrict__ twd,
                                                  float4* __restrict__ sel) {
    int s   = blockIdx.x;            // series id = b*512 + d
    int tid = threadIdx.x;

    __shared__ float   xs[T_LEN];          // 4 KB
    __shared__ double2 ys[32][33];         // 16.9 KB  [k1][t0] padded
    __shared__ double2 w32s[32];           // 0.5 KB
    __shared__ double  magd[512];          // 4 KB
    __shared__ float2  cval[512];          // 4 KB
    __shared__ double  redm[4];
    __shared__ int     redk[4];

    // load series (contiguous, coalesced)
    const float* xp = xT + (size_t)s * T_LEN;
#pragma unroll
    for (int i = 0; i < 4; i++) xs[tid + 256 * i] = xp[tid + 256 * i];
    if (tid < 32) w32s[tid] = twd[tid * 32];   // e^{-2pi i k1/32}
    __syncthreads();

    // ---- phase A: inner 32-pt DFTs.  y[k1][t0] = sum_t1 x[32*t1+t0] * W32^{k1*t1}
    {
        int k1  = tid & 31;
        int t0b = (tid >> 5) * 4;    // this thread owns t0b..t0b+3
        double yr0 = 0, yi0 = 0, yr1 = 0, yi1 = 0;
        double yr2 = 0, yi2 = 0, yr3 = 0, yi3 = 0;
        double2 st = w32s[k1];
        double wr = 1.0, wi = 0.0;
#pragma unroll
        for (int t1 = 0; t1 < 32; t1++) {
            const float* xq = &xs[32 * t1 + t0b];
            double x0 = (double)xq[0], x1 = (double)xq[1];
            double x2 = (double)xq[2], x3 = (double)xq[3];
            yr0 += x0 * wr; yi0 += x0 * wi;
            yr1 += x1 * wr; yi1 += x1 * wi;
            yr2 += x2 * wr; yi2 += x2 * wi;
            yr3 += x3 * wr; yi3 += x3 * wi;
            double nwr = wr * st.x - wi * st.y;
            double nwi = wr * st.y + wi * st.x;
            wr = nwr; wi = nwi;
        }
        ys[k1][t0b + 0] = make_double2(yr0, yi0);
        ys[k1][t0b + 1] = make_double2(yr1, yi1);
        ys[k1][t0b + 2] = make_double2(yr2, yi2);
        ys[k1][t0b + 3] = make_double2(yr3, yi3);
    }
    __syncthreads();

    // ---- phase B: c_k = sum_t0 y[k&31][t0] * W^{k*t0},  k = tid, tid+256
    {
        const float scale = 2.0f / (float)T_LEN;
#pragma unroll
        for (int kk = 0; kk < 2; kk++) {
            int k  = tid + kk * 256;
            int k1 = k & 31;
            double2 st = twd[k];     // e^{-2pi i k/1024}
            double wr = 1.0, wi = 0.0, cr = 0.0, ci = 0.0;
#pragma unroll
            for (int t0 = 0; t0 < 32; t0++) {
                double2 y = ys[k1][t0];
                cr += y.x * wr - y.y * wi;
                ci += y.x * wi + y.y * wr;
                double nwr = wr * st.x - wi * st.y;
                double nwi = wr * st.y + wi * st.x;
                wr = nwr; wi = nwi;
            }
            magd[k] = (k == 0) ? -1.0 : (cr * cr + ci * ci);  // exclude DC
            cval[k] = make_float2((float)(cr * (double)scale),
                                  (float)(ci * (double)scale));
        }
    }
    __syncthreads();

    // ---- top-16 (argmax rounds; ties -> lower k, matching lax.top_k) ----
    for (int r = 0; r < 16; r++) {
        double bm = -2.0; int bk = 0;
        {
            double m = magd[tid];
            if (m > bm) { bm = m; bk = tid; }
        }
        {
            int k = tid + 256;
            double m = magd[k];
            if (m > bm || (m == bm && k < bk)) { bm = m; bk = k; }
        }
#pragma unroll
        for (int off = 1; off <= 32; off <<= 1) {
            double om = __shfl_xor(bm, off);
            int    ok = __shfl_xor(bk, off);
            if (om > bm || (om == bm && ok < bk)) { bm = om; bk = ok; }
        }
        if ((tid & 63) == 0) { redm[tid >> 6] = bm; redk[tid >> 6] = bk; }
        __syncthreads();
        if (tid == 0) {
#pragma unroll
            for (int j = 1; j < 4; j++) {
                if (redm[j] > bm || (redm[j] == bm && redk[j] < bk)) {
                    bm = redm[j]; bk = redk[j];
                }
            }
            magd[bk] = -1.0;                       // mark taken
            float2 v = cval[bk];
            sel[(size_t)s * K_SEL + r] = make_float4((float)bk, v.x, v.y, 0.0f);
        }
        __syncthreads();
    }
}

// ---------------- kernel 2: sparse inverse reconstruction ----------------
__global__ __launch_bounds__(256) void k_recon(const float4* __restrict__ sel,
                                               const float2* __restrict__ twf,
                                               float* __restrict__ out) {
    int blk = blockIdx.x;            // b(16) * dblk(8) * tchunk(4) = 512
    int b    = blk >> 5;
    int dblk = (blk >> 2) & 7;
    int tc   = blk & 3;
    int tid  = threadIdx.x;
    int dd   = tid & 63;             // d within 64-wide tile
    int tg   = tid >> 6;             // 0..3 time-phase

    __shared__ float4 ssel[64][17];  // padded
    __shared__ float2 vt[T_LEN];     // V^m table, 8 KB

#pragma unroll
    for (int i = 0; i < 4; i++) vt[tid + 256 * i] = twf[tid + 256 * i];
    int d0 = dblk * 64;
#pragma unroll
    for (int i = 0; i < 4; i++) {
        int l = tid + 256 * i;       // 1024 entries = 64 series * 16
        int sdd = l >> 4, j = l & 15;
        ssel[sdd][j] = sel[((size_t)(b * D_DIM + d0 + sdd)) * K_SEL + j];
    }
    __syncthreads();

    int tstart = tc * 256 + tg;
    float zr[16], zi[16], sr[16], si[16];
#pragma unroll
    for (int j = 0; j < 16; j++) {
        float4 e = ssel[dd][j];
        int k = (int)e.x;
        float2 v0 = vt[(k * tstart) & (T_LEN - 1)];
        zr[j] = e.y * v0.x - e.z * v0.y;   // z = c * V^{k*tstart}
        zi[j] = e.y * v0.y + e.z * v0.x;
        float2 st = vt[(k * 4) & (T_LEN - 1)];
        sr[j] = st.x; si[j] = st.y;        // step V^{4k}
    }

    float* ob = out + (size_t)b * OUT_T * D_DIM + (d0 + dd);
    for (int it = 0; it < 64; it++) {
        int t = tstart + it * 4;
        float v = 0.0f;
#pragma unroll
        for (int j = 0; j < 16; j++) {
            v += zr[j];
            float nr = zr[j] * sr[j] - zi[j] * si[j];
            float ni = zr[j] * si[j] + zi[j] * sr[j];
            zr[j] = nr; zi[j] = ni;
        }
        ob[(size_t)t * D_DIM] = v;
        if (t < OUT_T - T_LEN)               // replicate t+1024 (periodicity)
            ob[(size_t)(t + T_LEN) * D_DIM] = v;
    }
}

// ---------------- launch ----------------
extern "C" void kernel_launch(void* const* d_in, const int* in_sizes, int n_in,
                              void* d_out, int out_size, void* d_ws, size_t ws_size,
                              hipStream_t stream) {
    (void)in_sizes; (void)n_in; (void)out_size; (void)ws_size;
    const float* x = (const float*)d_in[0];
    float* out = (float*)d_out;
    char* ws = (char*)d_ws;

    double2* twd = (double2*)ws;
    float2*  twf = (float2*)(ws + 16384);
    float4*  sel = (float4*)(ws + 24576);
    float*   xT  = out;   // reuse output buffer as transpose scratch (32MB < 40MB)

    hipLaunchKernelGGL(k_tables,    dim3(4),    dim3(256), 0, stream, twd, twf);
    hipLaunchKernelGGL(k_transpose, dim3(8192), dim3(256), 0, stream, x, xT);
    hipLaunchKernelGGL(k_dft_topk,  dim3(8192), dim3(256), 0, stream, xT, twd, sel);
    hipLaunchKernelGGL(k_recon,     dim3(512),  dim3(256), 0, stream, sel, twf, out);
}